// Round 1
// baseline (469.988 us; speedup 1.0000x reference)
//
#include <hip/hip_runtime.h>
#include <math.h>

#define NP 16384
#define NG 2048
#define NC 17

#define GRIDSZ 0.4f
#define PCMINX -40.0f
#define PCMINY -40.0f
#define PCMINZ -1.0f
#define SCALE_MULTC 3.0f

// fp layout per primitive (20 floats):
// [0:3]  murot_i = sum_j mu_j * rot[j*3+i]
// [3:12] rot (row-major, rot[j*3+i])
// [12:15] scales
// [15] opa, [16] 1/u, [17] 1/v, [18] v/u, [19] pad
__global__ void prep_kernel(const float* __restrict__ means3D,
                            const float* __restrict__ opas,
                            const float* __restrict__ uu,
                            const float* __restrict__ vv,
                            const float* __restrict__ scales,
                            const float* __restrict__ rot3D,
                            int4* __restrict__ mi4,
                            float* __restrict__ fp) {
    int g = blockIdx.x * blockDim.x + threadIdx.x;
    if (g >= NG) return;
    float mx = means3D[g * 3 + 0], my = means3D[g * 3 + 1], mz = means3D[g * 3 + 2];
    float sx = scales[g * 3 + 0], sy = scales[g * 3 + 1], sz = scales[g * 3 + 2];
    float r[9];
#pragma unroll
    for (int i = 0; i < 9; ++i) r[i] = rot3D[g * 9 + i];

    int4 m;
    m.x = (int)floorf((mx - PCMINX) / GRIDSZ);
    m.y = (int)floorf((my - PCMINY) / GRIDSZ);
    m.z = (int)floorf((mz - PCMINZ) / GRIDSZ);
    float smax = fmaxf(sx, fmaxf(sy, sz));
    int rad = (int)ceilf(smax * SCALE_MULTC / GRIDSZ);
    m.w = rad < 1 ? 1 : rad;
    mi4[g] = m;

    float* o = fp + (size_t)g * 20;
#pragma unroll
    for (int i = 0; i < 3; ++i)
        o[i] = mx * r[0 * 3 + i] + my * r[1 * 3 + i] + mz * r[2 * 3 + i];
#pragma unroll
    for (int i = 0; i < 9; ++i) o[3 + i] = r[i];
    o[12] = sx; o[13] = sy; o[14] = sz;
    o[15] = opas[g];
    o[16] = 1.0f / uu[g];
    o[17] = 1.0f / vv[g];
    o[18] = vv[g] / uu[g];
    o[19] = 0.0f;
}

template <bool PRE>
__global__ __launch_bounds__(64)
void agg_kernel(const float* __restrict__ pts,
                const float* __restrict__ means3D,
                const float* __restrict__ opas,
                const float* __restrict__ uu,
                const float* __restrict__ vv,
                const float* __restrict__ semantics,
                const float* __restrict__ scales,
                const float* __restrict__ rot3D,
                const int4* __restrict__ mi4,
                const float* __restrict__ fp,
                float* __restrict__ out) {
    int p = blockIdx.x * 64 + threadIdx.x;
    if (p >= NP) return;

    float px = pts[p * 3 + 0], py = pts[p * 3 + 1], pz = pts[p * 3 + 2];
    int pix = (int)floorf((px - PCMINX) / GRIDSZ);
    int piy = (int)floorf((py - PCMINY) / GRIDSZ);
    int piz = (int)floorf((pz - PCMINZ) / GRIDSZ);

    float density = 0.0f;
    float logbin = 0.0f;
    float acc[NC];
#pragma unroll
    for (int c = 0; c < NC; ++c) acc[c] = 0.0f;

#pragma unroll 4
    for (int g = 0; g < NG; ++g) {
        int mx, my, mz, rad;
        if (PRE) {
            int4 m = mi4[g];
            mx = m.x; my = m.y; mz = m.z; rad = m.w;
        } else {
            float cx = means3D[g * 3 + 0], cy = means3D[g * 3 + 1], cz = means3D[g * 3 + 2];
            mx = (int)floorf((cx - PCMINX) / GRIDSZ);
            my = (int)floorf((cy - PCMINY) / GRIDSZ);
            mz = (int)floorf((cz - PCMINZ) / GRIDSZ);
            float smax = fmaxf(scales[g * 3 + 0], fmaxf(scales[g * 3 + 1], scales[g * 3 + 2]));
            rad = (int)ceilf(smax * SCALE_MULTC / GRIDSZ);
            rad = rad < 1 ? 1 : rad;
        }
        int cheb = max(abs(pix - mx), max(abs(piy - my), abs(piz - mz)));
        if (cheb <= rad) {
            float l0, l1, l2, sc0, sc1, sc2, opa, ie1, ie2, e21;
            if (PRE) {
                const float* o = fp + (size_t)g * 20;
                l0 = px * o[3] + py * o[6] + pz * o[9]  - o[0];
                l1 = px * o[4] + py * o[7] + pz * o[10] - o[1];
                l2 = px * o[5] + py * o[8] + pz * o[11] - o[2];
                sc0 = o[12]; sc1 = o[13]; sc2 = o[14];
                opa = o[15]; ie1 = o[16]; ie2 = o[17]; e21 = o[18];
            } else {
                const float* r = rot3D + (size_t)g * 9;
                float cx = means3D[g * 3 + 0], cy = means3D[g * 3 + 1], cz = means3D[g * 3 + 2];
                float dx = px - cx, dy = py - cy, dz = pz - cz;
                l0 = dx * r[0] + dy * r[3] + dz * r[6];
                l1 = dx * r[1] + dy * r[4] + dz * r[7];
                l2 = dx * r[2] + dy * r[5] + dz * r[8];
                sc0 = scales[g * 3 + 0]; sc1 = scales[g * 3 + 1]; sc2 = scales[g * 3 + 2];
                opa = opas[g];
                ie1 = 1.0f / uu[g]; ie2 = 1.0f / vv[g]; e21 = vv[g] / uu[g];
            }
            float t0 = l0 / sc0, t1 = l1 / sc1, t2 = l2 / sc2;
            float s0 = t0 * t0 + 1e-8f;
            float s1 = t1 * t1 + 1e-8f;
            float s2 = t2 * t2 + 1e-8f;
            float f = powf(powf(s0, ie2) + powf(s1, ie2), e21) + powf(s2, ie1);
            float a = opa * expf(-0.5f * f);

            density += a;
            const float* sg = semantics + (size_t)g * NC;
#pragma unroll
            for (int c = 0; c < NC; ++c) acc[c] = fmaf(a, sg[c], acc[c]);
            float a_c = fminf(a, 1.0f - 1e-4f);
            logbin += log1pf(-a_c);
        }
    }

    float inv = 1.0f / (density + 1e-9f);
#pragma unroll
    for (int c = 0; c < NC; ++c) out[(size_t)p * NC + c] = acc[c] * inv;
    out[(size_t)NP * NC + p] = 1.0f - expf(logbin);
    out[(size_t)NP * NC + NP + p] = density;
}

extern "C" void kernel_launch(void* const* d_in, const int* in_sizes, int n_in,
                              void* d_out, int out_size, void* d_ws, size_t ws_size,
                              hipStream_t stream) {
    const float* pts       = (const float*)d_in[0];
    const float* means3D   = (const float*)d_in[1];
    const float* opas      = (const float*)d_in[2];
    const float* uu        = (const float*)d_in[3];
    const float* vv        = (const float*)d_in[4];
    const float* semantics = (const float*)d_in[5];
    const float* scales    = (const float*)d_in[6];
    const float* rot3D     = (const float*)d_in[7];
    float* out = (float*)d_out;

    size_t need = (size_t)NG * sizeof(int4) + (size_t)NG * 20 * sizeof(float);
    if (ws_size >= need) {
        int4* mi4 = (int4*)d_ws;
        float* fp = (float*)((char*)d_ws + (size_t)NG * sizeof(int4));
        prep_kernel<<<(NG + 255) / 256, 256, 0, stream>>>(means3D, opas, uu, vv, scales,
                                                          rot3D, mi4, fp);
        agg_kernel<true><<<NP / 64, 64, 0, stream>>>(pts, means3D, opas, uu, vv, semantics,
                                                     scales, rot3D, mi4, fp, out);
    } else {
        agg_kernel<false><<<NP / 64, 64, 0, stream>>>(pts, means3D, opas, uu, vv, semantics,
                                                      scales, rot3D, (const int4*)nullptr,
                                                      (const float*)nullptr, out);
    }
}

// Round 2
// 110.377 us; speedup vs baseline: 4.2580x; 4.2580x over previous
//
#include <hip/hip_runtime.h>
#include <math.h>

#define NP 16384
#define NG 2048
#define NC 17
#define NPB 64      // NP / 256 point-blocks
#define NSPLIT 16   // G-chunks
#define CHUNK 128   // NG / NSPLIT

#define GRIDSZ 0.4f
#define PCMINX -40.0f
#define PCMINY -40.0f
#define PCMINZ -1.0f
#define SCALE_MULTC 3.0f

// fp layout per primitive (20 floats):
// [0:3]  murot_i = sum_j mu_j * rot[j*3+i]
// [3:12] rot (row-major, rot[j*3+i])
// [12:15] 1/scales
// [15] opa, [16] 1/u, [17] 1/v, [18] v/u, [19] pad
__global__ void prep_kernel(const float* __restrict__ means3D,
                            const float* __restrict__ opas,
                            const float* __restrict__ uu,
                            const float* __restrict__ vv,
                            const float* __restrict__ scales,
                            const float* __restrict__ rot3D,
                            int4* __restrict__ mi4,
                            float* __restrict__ fp) {
    int g = blockIdx.x * blockDim.x + threadIdx.x;
    if (g >= NG) return;
    float mx = means3D[g * 3 + 0], my = means3D[g * 3 + 1], mz = means3D[g * 3 + 2];
    float sx = scales[g * 3 + 0], sy = scales[g * 3 + 1], sz = scales[g * 3 + 2];
    float r[9];
#pragma unroll
    for (int i = 0; i < 9; ++i) r[i] = rot3D[g * 9 + i];

    int4 m;
    m.x = (int)floorf((mx - PCMINX) / GRIDSZ);
    m.y = (int)floorf((my - PCMINY) / GRIDSZ);
    m.z = (int)floorf((mz - PCMINZ) / GRIDSZ);
    float smax = fmaxf(sx, fmaxf(sy, sz));
    int rad = (int)ceilf(smax * SCALE_MULTC / GRIDSZ);
    m.w = rad < 1 ? 1 : rad;
    mi4[g] = m;

    float* o = fp + (size_t)g * 20;
#pragma unroll
    for (int i = 0; i < 3; ++i)
        o[i] = mx * r[0 * 3 + i] + my * r[1 * 3 + i] + mz * r[2 * 3 + i];
#pragma unroll
    for (int i = 0; i < 9; ++i) o[3 + i] = r[i];
    o[12] = 1.0f / sx; o[13] = 1.0f / sy; o[14] = 1.0f / sz;
    o[15] = opas[g];
    o[16] = 1.0f / uu[g];
    o[17] = 1.0f / vv[g];
    o[18] = vv[g] / uu[g];
    o[19] = 0.0f;
}

// One block = 256 points x one 128-primitive chunk. Partials to ws.
__global__ __launch_bounds__(256)
void agg_part_kernel(const float* __restrict__ pts,
                     const float* __restrict__ semantics,
                     const int4* __restrict__ mi4,
                     const float* __restrict__ fp,
                     float* __restrict__ part) {
    __shared__ int4 smi[CHUNK];
    __shared__ float sfp[CHUNK * 20];
    int tid = threadIdx.x;
    int pb = blockIdx.x & (NPB - 1);
    int cs = blockIdx.x >> 6;
    int g0 = cs * CHUNK;

    for (int i = tid; i < CHUNK; i += 256) smi[i] = mi4[g0 + i];
    for (int i = tid; i < CHUNK * 20; i += 256) sfp[i] = fp[(size_t)g0 * 20 + i];
    __syncthreads();

    int p = pb * 256 + tid;
    float px = pts[p * 3 + 0], py = pts[p * 3 + 1], pz = pts[p * 3 + 2];
    int pix = (int)floorf((px - PCMINX) / GRIDSZ);
    int piy = (int)floorf((py - PCMINY) / GRIDSZ);
    int piz = (int)floorf((pz - PCMINZ) / GRIDSZ);

    float density = 0.0f, logbin = 0.0f;
    float acc[NC];
#pragma unroll
    for (int c = 0; c < NC; ++c) acc[c] = 0.0f;

#pragma unroll 4
    for (int g = 0; g < CHUNK; ++g) {
        int4 m = smi[g];
        int cheb = max(abs(pix - m.x), max(abs(piy - m.y), abs(piz - m.z)));
        if (cheb <= m.w) {
            const float* o = sfp + g * 20;
            float l0 = px * o[3] + py * o[6] + pz * o[9]  - o[0];
            float l1 = px * o[4] + py * o[7] + pz * o[10] - o[1];
            float l2 = px * o[5] + py * o[8] + pz * o[11] - o[2];
            float t0 = l0 * o[12], t1 = l1 * o[13], t2 = l2 * o[14];
            float s0 = t0 * t0 + 1e-8f;
            float s1 = t1 * t1 + 1e-8f;
            float s2 = t2 * t2 + 1e-8f;
            float f = __powf(__powf(s0, o[17]) + __powf(s1, o[17]), o[18]) +
                      __powf(s2, o[16]);
            float a = o[15] * __expf(-0.5f * f);
            density += a;
            const float* sg = semantics + (size_t)(g0 + g) * NC;
#pragma unroll
            for (int c = 0; c < NC; ++c) acc[c] = fmaf(a, sg[c], acc[c]);
            logbin += log1pf(-fminf(a, 1.0f - 1e-4f));
        }
    }

    float* pp = part + (size_t)cs * 19 * NP + p;
#pragma unroll
    for (int j = 0; j < NC; ++j) pp[(size_t)j * NP] = acc[j];
    pp[(size_t)17 * NP] = density;
    pp[(size_t)18 * NP] = logbin;
}

__global__ __launch_bounds__(256)
void finalize_kernel(const float* __restrict__ part, float* __restrict__ out) {
    int p = blockIdx.x * 256 + threadIdx.x;
    float density = 0.0f, logbin = 0.0f;
    float acc[NC];
#pragma unroll
    for (int c = 0; c < NC; ++c) acc[c] = 0.0f;

    for (int cs = 0; cs < NSPLIT; ++cs) {
        const float* pp = part + (size_t)cs * 19 * NP + p;
#pragma unroll
        for (int j = 0; j < NC; ++j) acc[j] += pp[(size_t)j * NP];
        density += pp[(size_t)17 * NP];
        logbin += pp[(size_t)18 * NP];
    }
    float inv = 1.0f / (density + 1e-9f);
#pragma unroll
    for (int c = 0; c < NC; ++c) out[(size_t)p * NC + c] = acc[c] * inv;
    out[(size_t)NP * NC + p] = 1.0f - expf(logbin);
    out[(size_t)NP * NC + NP + p] = density;
}

// ---- fallback (ws too small): round-1 style monolithic kernel ----
__global__ __launch_bounds__(64)
void agg_kernel_fb(const float* __restrict__ pts,
                   const float* __restrict__ means3D,
                   const float* __restrict__ opas,
                   const float* __restrict__ uu,
                   const float* __restrict__ vv,
                   const float* __restrict__ semantics,
                   const float* __restrict__ scales,
                   const float* __restrict__ rot3D,
                   float* __restrict__ out) {
    int p = blockIdx.x * 64 + threadIdx.x;
    if (p >= NP) return;
    float px = pts[p * 3 + 0], py = pts[p * 3 + 1], pz = pts[p * 3 + 2];
    int pix = (int)floorf((px - PCMINX) / GRIDSZ);
    int piy = (int)floorf((py - PCMINY) / GRIDSZ);
    int piz = (int)floorf((pz - PCMINZ) / GRIDSZ);
    float density = 0.0f, logbin = 0.0f;
    float acc[NC];
#pragma unroll
    for (int c = 0; c < NC; ++c) acc[c] = 0.0f;
    for (int g = 0; g < NG; ++g) {
        float cx = means3D[g * 3 + 0], cy = means3D[g * 3 + 1], cz = means3D[g * 3 + 2];
        int mx = (int)floorf((cx - PCMINX) / GRIDSZ);
        int my = (int)floorf((cy - PCMINY) / GRIDSZ);
        int mz = (int)floorf((cz - PCMINZ) / GRIDSZ);
        float smax = fmaxf(scales[g * 3 + 0], fmaxf(scales[g * 3 + 1], scales[g * 3 + 2]));
        int rad = (int)ceilf(smax * SCALE_MULTC / GRIDSZ);
        rad = rad < 1 ? 1 : rad;
        int cheb = max(abs(pix - mx), max(abs(piy - my), abs(piz - mz)));
        if (cheb <= rad) {
            const float* r = rot3D + (size_t)g * 9;
            float dx = px - cx, dy = py - cy, dz = pz - cz;
            float l0 = dx * r[0] + dy * r[3] + dz * r[6];
            float l1 = dx * r[1] + dy * r[4] + dz * r[7];
            float l2 = dx * r[2] + dy * r[5] + dz * r[8];
            float t0 = l0 / scales[g * 3 + 0], t1 = l1 / scales[g * 3 + 1], t2 = l2 / scales[g * 3 + 2];
            float s0 = t0 * t0 + 1e-8f, s1 = t1 * t1 + 1e-8f, s2 = t2 * t2 + 1e-8f;
            float ie1 = 1.0f / uu[g], ie2 = 1.0f / vv[g], e21 = vv[g] / uu[g];
            float f = powf(powf(s0, ie2) + powf(s1, ie2), e21) + powf(s2, ie1);
            float a = opas[g] * expf(-0.5f * f);
            density += a;
            const float* sg = semantics + (size_t)g * NC;
#pragma unroll
            for (int c = 0; c < NC; ++c) acc[c] = fmaf(a, sg[c], acc[c]);
            logbin += log1pf(-fminf(a, 1.0f - 1e-4f));
        }
    }
    float inv = 1.0f / (density + 1e-9f);
#pragma unroll
    for (int c = 0; c < NC; ++c) out[(size_t)p * NC + c] = acc[c] * inv;
    out[(size_t)NP * NC + p] = 1.0f - expf(logbin);
    out[(size_t)NP * NC + NP + p] = density;
}

extern "C" void kernel_launch(void* const* d_in, const int* in_sizes, int n_in,
                              void* d_out, int out_size, void* d_ws, size_t ws_size,
                              hipStream_t stream) {
    const float* pts       = (const float*)d_in[0];
    const float* means3D   = (const float*)d_in[1];
    const float* opas      = (const float*)d_in[2];
    const float* uu        = (const float*)d_in[3];
    const float* vv        = (const float*)d_in[4];
    const float* semantics = (const float*)d_in[5];
    const float* scales    = (const float*)d_in[6];
    const float* rot3D     = (const float*)d_in[7];
    float* out = (float*)d_out;

    size_t prep_bytes = (size_t)NG * sizeof(int4) + (size_t)NG * 20 * sizeof(float); // 196608
    size_t part_bytes = (size_t)NSPLIT * 19 * NP * sizeof(float);                    // ~19.9 MB

    if (ws_size >= prep_bytes + part_bytes) {
        int4* mi4 = (int4*)d_ws;
        float* fp = (float*)((char*)d_ws + (size_t)NG * sizeof(int4));
        float* part = (float*)((char*)d_ws + prep_bytes);
        prep_kernel<<<(NG + 255) / 256, 256, 0, stream>>>(means3D, opas, uu, vv, scales,
                                                          rot3D, mi4, fp);
        agg_part_kernel<<<NPB * NSPLIT, 256, 0, stream>>>(pts, semantics, mi4, fp, part);
        finalize_kernel<<<NP / 256, 256, 0, stream>>>(part, out);
    } else {
        agg_kernel_fb<<<NP / 64, 64, 0, stream>>>(pts, means3D, opas, uu, vv, semantics,
                                                  scales, rot3D, out);
    }
}

// Round 3
// 48.624 us; speedup vs baseline: 9.6658x; 2.2700x over previous
//
#include <hip/hip_runtime.h>
#include <math.h>

#define NP 16384
#define NG 2048
#define NC 17
#define NPB 64      // NP / 256 point-blocks
#define NSPLIT 16   // G-chunks
#define CHUNK 128   // NG / NSPLIT

#define GRIDSZ 0.4f
#define PCMINX -40.0f
#define PCMINY -40.0f
#define PCMINZ -1.0f
#define SCALE_MULTC 3.0f

// fp layout per primitive (20 floats):
// [0:3]  murot_i = sum_j mu_j * rot[j*3+i]
// [3:12] rot (row-major, rot[j*3+i])
// [12:15] 1/scales
// [15] opa, [16] 1/u, [17] 1/v, [18] v/u, [19] pad
__global__ void prep_kernel(const float* __restrict__ means3D,
                            const float* __restrict__ opas,
                            const float* __restrict__ uu,
                            const float* __restrict__ vv,
                            const float* __restrict__ scales,
                            const float* __restrict__ rot3D,
                            int4* __restrict__ mi4,
                            float* __restrict__ fp) {
    int g = blockIdx.x * blockDim.x + threadIdx.x;
    if (g >= NG) return;
    float mx = means3D[g * 3 + 0], my = means3D[g * 3 + 1], mz = means3D[g * 3 + 2];
    float sx = scales[g * 3 + 0], sy = scales[g * 3 + 1], sz = scales[g * 3 + 2];
    float r[9];
#pragma unroll
    for (int i = 0; i < 9; ++i) r[i] = rot3D[g * 9 + i];

    int4 m;
    m.x = (int)floorf((mx - PCMINX) / GRIDSZ);
    m.y = (int)floorf((my - PCMINY) / GRIDSZ);
    m.z = (int)floorf((mz - PCMINZ) / GRIDSZ);
    float smax = fmaxf(sx, fmaxf(sy, sz));
    int rad = (int)ceilf(smax * SCALE_MULTC / GRIDSZ);
    m.w = rad < 1 ? 1 : rad;
    mi4[g] = m;

    float* o = fp + (size_t)g * 20;
#pragma unroll
    for (int i = 0; i < 3; ++i)
        o[i] = mx * r[0 * 3 + i] + my * r[1 * 3 + i] + mz * r[2 * 3 + i];
#pragma unroll
    for (int i = 0; i < 9; ++i) o[3 + i] = r[i];
    o[12] = 1.0f / sx; o[13] = 1.0f / sy; o[14] = 1.0f / sz;
    o[15] = opas[g];
    o[16] = 1.0f / uu[g];
    o[17] = 1.0f / vv[g];
    o[18] = vv[g] / uu[g];
    o[19] = 0.0f;
}

// One block = 256 points x one 128-primitive chunk. Partials to ws.
// Pass 1: branchless 128-bit hit mask. Pass 2: iterate set bits only.
__global__ __launch_bounds__(256)
void agg_part_kernel(const float* __restrict__ pts,
                     const float* __restrict__ semantics,
                     const int4* __restrict__ mi4,
                     const float* __restrict__ fp,
                     float* __restrict__ part) {
    __shared__ int4 smi[CHUNK];
    __shared__ float sfp[CHUNK * 20];
    int tid = threadIdx.x;
    int pb = blockIdx.x & (NPB - 1);
    int cs = blockIdx.x >> 6;
    int g0 = cs * CHUNK;

    for (int i = tid; i < CHUNK; i += 256) smi[i] = mi4[g0 + i];
    for (int i = tid; i < CHUNK * 20; i += 256) sfp[i] = fp[(size_t)g0 * 20 + i];
    __syncthreads();

    int p = pb * 256 + tid;
    float px = pts[p * 3 + 0], py = pts[p * 3 + 1], pz = pts[p * 3 + 2];
    int pix = (int)floorf((px - PCMINX) / GRIDSZ);
    int piy = (int)floorf((py - PCMINY) / GRIDSZ);
    int piz = (int)floorf((pz - PCMINZ) / GRIDSZ);

    // ---- pass 1: branchless hit masks (nothing heavy to speculate) ----
    unsigned long long msk0 = 0ull, msk1 = 0ull;
#pragma unroll 8
    for (int g = 0; g < 64; ++g) {
        int4 m = smi[g];
        int cheb = max(max(abs(pix - m.x), abs(piy - m.y)), abs(piz - m.z));
        msk0 |= (unsigned long long)(cheb <= m.w) << g;
    }
#pragma unroll 8
    for (int g = 64; g < CHUNK; ++g) {
        int4 m = smi[g];
        int cheb = max(max(abs(pix - m.x), abs(piy - m.y)), abs(piz - m.z));
        msk1 |= (unsigned long long)(cheb <= m.w) << (g - 64);
    }

    float density = 0.0f, logbin = 0.0f;
    float acc[NC];
#pragma unroll
    for (int c = 0; c < NC; ++c) acc[c] = 0.0f;

    // ---- pass 2: process only set bits ----
#pragma unroll 1
    for (int half = 0; half < 2; ++half) {
        unsigned long long msk = half ? msk1 : msk0;
        int gb = g0 + (half ? 64 : 0);
        int lb = half ? 64 : 0;
        while (msk) {
            int g = __builtin_ctzll(msk);
            msk &= msk - 1;
            const float* o = sfp + (lb + g) * 20;
            float l0 = px * o[3] + py * o[6] + pz * o[9]  - o[0];
            float l1 = px * o[4] + py * o[7] + pz * o[10] - o[1];
            float l2 = px * o[5] + py * o[8] + pz * o[11] - o[2];
            float t0 = l0 * o[12], t1 = l1 * o[13], t2 = l2 * o[14];
            float s0 = t0 * t0 + 1e-8f;
            float s1 = t1 * t1 + 1e-8f;
            float s2 = t2 * t2 + 1e-8f;
            float f = __powf(__powf(s0, o[17]) + __powf(s1, o[17]), o[18]) +
                      __powf(s2, o[16]);
            float a = o[15] * __expf(-0.5f * f);
            density += a;
            const float* sg = semantics + (size_t)(gb + g) * NC;
#pragma unroll
            for (int c = 0; c < NC; ++c) acc[c] = fmaf(a, sg[c], acc[c]);
            logbin += __logf(1.0f - fminf(a, 1.0f - 1e-4f));
        }
    }

    float* pp = part + (size_t)cs * 19 * NP + p;
#pragma unroll
    for (int j = 0; j < NC; ++j) pp[(size_t)j * NP] = acc[j];
    pp[(size_t)17 * NP] = density;
    pp[(size_t)18 * NP] = logbin;
}

__global__ __launch_bounds__(256)
void finalize_kernel(const float* __restrict__ part, float* __restrict__ out) {
    int p = blockIdx.x * 256 + threadIdx.x;
    float density = 0.0f, logbin = 0.0f;
    float acc[NC];
#pragma unroll
    for (int c = 0; c < NC; ++c) acc[c] = 0.0f;

    for (int cs = 0; cs < NSPLIT; ++cs) {
        const float* pp = part + (size_t)cs * 19 * NP + p;
#pragma unroll
        for (int j = 0; j < NC; ++j) acc[j] += pp[(size_t)j * NP];
        density += pp[(size_t)17 * NP];
        logbin += pp[(size_t)18 * NP];
    }
    float inv = 1.0f / (density + 1e-9f);
#pragma unroll
    for (int c = 0; c < NC; ++c) out[(size_t)p * NC + c] = acc[c] * inv;
    out[(size_t)NP * NC + p] = 1.0f - expf(logbin);
    out[(size_t)NP * NC + NP + p] = density;
}

// ---- fallback (ws too small): monolithic kernel ----
__global__ __launch_bounds__(64)
void agg_kernel_fb(const float* __restrict__ pts,
                   const float* __restrict__ means3D,
                   const float* __restrict__ opas,
                   const float* __restrict__ uu,
                   const float* __restrict__ vv,
                   const float* __restrict__ semantics,
                   const float* __restrict__ scales,
                   const float* __restrict__ rot3D,
                   float* __restrict__ out) {
    int p = blockIdx.x * 64 + threadIdx.x;
    if (p >= NP) return;
    float px = pts[p * 3 + 0], py = pts[p * 3 + 1], pz = pts[p * 3 + 2];
    int pix = (int)floorf((px - PCMINX) / GRIDSZ);
    int piy = (int)floorf((py - PCMINY) / GRIDSZ);
    int piz = (int)floorf((pz - PCMINZ) / GRIDSZ);
    float density = 0.0f, logbin = 0.0f;
    float acc[NC];
#pragma unroll
    for (int c = 0; c < NC; ++c) acc[c] = 0.0f;
    for (int g = 0; g < NG; ++g) {
        float cx = means3D[g * 3 + 0], cy = means3D[g * 3 + 1], cz = means3D[g * 3 + 2];
        int mx = (int)floorf((cx - PCMINX) / GRIDSZ);
        int my = (int)floorf((cy - PCMINY) / GRIDSZ);
        int mz = (int)floorf((cz - PCMINZ) / GRIDSZ);
        float smax = fmaxf(scales[g * 3 + 0], fmaxf(scales[g * 3 + 1], scales[g * 3 + 2]));
        int rad = (int)ceilf(smax * SCALE_MULTC / GRIDSZ);
        rad = rad < 1 ? 1 : rad;
        int cheb = max(abs(pix - mx), max(abs(piy - my), abs(piz - mz)));
        if (cheb <= rad) {
            const float* r = rot3D + (size_t)g * 9;
            float dx = px - cx, dy = py - cy, dz = pz - cz;
            float l0 = dx * r[0] + dy * r[3] + dz * r[6];
            float l1 = dx * r[1] + dy * r[4] + dz * r[7];
            float l2 = dx * r[2] + dy * r[5] + dz * r[8];
            float t0 = l0 / scales[g * 3 + 0], t1 = l1 / scales[g * 3 + 1], t2 = l2 / scales[g * 3 + 2];
            float s0 = t0 * t0 + 1e-8f, s1 = t1 * t1 + 1e-8f, s2 = t2 * t2 + 1e-8f;
            float ie1 = 1.0f / uu[g], ie2 = 1.0f / vv[g], e21 = vv[g] / uu[g];
            float f = powf(powf(s0, ie2) + powf(s1, ie2), e21) + powf(s2, ie1);
            float a = opas[g] * expf(-0.5f * f);
            density += a;
            const float* sg = semantics + (size_t)g * NC;
#pragma unroll
            for (int c = 0; c < NC; ++c) acc[c] = fmaf(a, sg[c], acc[c]);
            logbin += log1pf(-fminf(a, 1.0f - 1e-4f));
        }
    }
    float inv = 1.0f / (density + 1e-9f);
#pragma unroll
    for (int c = 0; c < NC; ++c) out[(size_t)p * NC + c] = acc[c] * inv;
    out[(size_t)NP * NC + p] = 1.0f - expf(logbin);
    out[(size_t)NP * NC + NP + p] = density;
}

extern "C" void kernel_launch(void* const* d_in, const int* in_sizes, int n_in,
                              void* d_out, int out_size, void* d_ws, size_t ws_size,
                              hipStream_t stream) {
    const float* pts       = (const float*)d_in[0];
    const float* means3D   = (const float*)d_in[1];
    const float* opas      = (const float*)d_in[2];
    const float* uu        = (const float*)d_in[3];
    const float* vv        = (const float*)d_in[4];
    const float* semantics = (const float*)d_in[5];
    const float* scales    = (const float*)d_in[6];
    const float* rot3D     = (const float*)d_in[7];
    float* out = (float*)d_out;

    size_t prep_bytes = (size_t)NG * sizeof(int4) + (size_t)NG * 20 * sizeof(float); // 196608
    size_t part_bytes = (size_t)NSPLIT * 19 * NP * sizeof(float);                    // ~19.9 MB

    if (ws_size >= prep_bytes + part_bytes) {
        int4* mi4 = (int4*)d_ws;
        float* fp = (float*)((char*)d_ws + (size_t)NG * sizeof(int4));
        float* part = (float*)((char*)d_ws + prep_bytes);
        prep_kernel<<<(NG + 255) / 256, 256, 0, stream>>>(means3D, opas, uu, vv, scales,
                                                          rot3D, mi4, fp);
        agg_part_kernel<<<NPB * NSPLIT, 256, 0, stream>>>(pts, semantics, mi4, fp, part);
        finalize_kernel<<<NP / 256, 256, 0, stream>>>(part, out);
    } else {
        agg_kernel_fb<<<NP / 64, 64, 0, stream>>>(pts, means3D, opas, uu, vv, semantics,
                                                  scales, rot3D, out);
    }
}